// Round 6
// baseline (301.189 us; speedup 1.0000x reference)
//
#include <hip/hip_runtime.h>

#define BB 16
#define NNODE 207
#define TTS 12
#define NE 1863
#define NEP2 1920 // NE padded to 30*64
#define NH 8
#define FD 768
#define HFD 6144
#define MM 3312   // BB*NNODE
#define MP 3328   // padded to 26*128

typedef short bf16x8 __attribute__((ext_vector_type(8)));
typedef float f32x4 __attribute__((ext_vector_type(4)));

typedef __attribute__((address_space(3))) unsigned int lds_u32;
typedef __attribute__((address_space(1))) const unsigned int glb_u32;

__device__ __forceinline__ unsigned short f2b(float f) {
    unsigned int u = __float_as_uint(f);
    u = (u + 0x7FFFu + ((u >> 16) & 1u)) >> 16;
    return (unsigned short)u;
}
__device__ __forceinline__ float b2f(unsigned short b) {
    return __uint_as_float(((unsigned int)b) << 16);
}

// ---------------- wl/wr precompute: wl[hh][k] = sum_f W[k][hh*768+f]*al[hh][f] --
// wlr layout: [which][2][8][768]  (wl then wr, per weight matrix)
__global__ __launch_bounds__(256) void prep_wlr(const float* __restrict__ W1,
                                                const float* __restrict__ al1, const float* __restrict__ ar1,
                                                const float* __restrict__ W2,
                                                const float* __restrict__ al2, const float* __restrict__ ar2,
                                                float* __restrict__ wlr) {
    const int d = blockIdx.x * 256 + threadIdx.x;   // 48 blocks -> 12288 = 2*768*8
    const int which = d / 6144;
    const int r = d % 6144;
    const int k = r >> 3, hh = r & 7;
    const float* W = which ? W2 : W1;
    const float* al = which ? al2 : al1;
    const float* ar = which ? ar2 : ar1;
    const float4* wp = (const float4*)(W + (size_t)k * HFD + hh * FD);
    const float4* ap = (const float4*)(al + hh * FD);
    const float4* rp = (const float4*)(ar + hh * FD);
    float sl = 0.f, sr = 0.f;
    for (int j = 0; j < 192; j++) {
        float4 w = wp[j], a = ap[j], b = rp[j];
        sl += w.x * a.x + w.y * a.y + w.z * a.z + w.w * a.w;
        sr += w.x * b.x + w.y * b.y + w.z * b.z + w.w * b.w;
    }
    wlr[(size_t)which * 12288 + 0 + hh * FD + k] = sl;
    wlr[(size_t)which * 12288 + 6144 + hh * FD + k] = sr;
}

// ---------------- W transpose (both weights): W[k][n] f32 -> Wt[n][k] bf16 -----
__global__ __launch_bounds__(256) void transpose_w2(const float* __restrict__ W1,
                                                    const float* __restrict__ W2,
                                                    unsigned short* __restrict__ Wt1,
                                                    unsigned short* __restrict__ Wt2) {
    __shared__ float tile[64][65];
    const float* W = blockIdx.z ? W2 : W1;
    unsigned short* Wt = blockIdx.z ? Wt2 : Wt1;
    const int k0 = blockIdx.x * 64;  // 768/64 = 12
    const int n0 = blockIdx.y * 64;  // 6144/64 = 96
    const int c = threadIdx.x & 63, r0 = threadIdx.x >> 6;
#pragma unroll
    for (int i = 0; i < 16; i++) {
        int r = r0 + i * 4;
        tile[r][c] = W[(size_t)(k0 + r) * HFD + n0 + c];
    }
    __syncthreads();
#pragma unroll
    for (int i = 0; i < 16; i++) {
        int r = r0 + i * 4;
        Wt[(size_t)(n0 + r) * FD + k0 + c] = f2b(tile[c][r]);
    }
}

// ---------------- 1x1 convs -> h0, hbf; fused layer-1 el/er --------------------
__global__ __launch_bounds__(256) void prep_h(const float* __restrict__ x,
                                              const float* __restrict__ Ws, const float* __restrict__ bs,
                                              const float* __restrict__ Wc, const float* __restrict__ bc,
                                              const float* __restrict__ wl, const float* __restrict__ wr,
                                              float* __restrict__ h0, unsigned short* __restrict__ hbf,
                                              float* __restrict__ el, float* __restrict__ er) {
    __shared__ float redl[4][8], redr[4][8];
    const int bn = blockIdx.x;
    const int t = threadIdx.x;
    if (bn >= MM) {
#pragma unroll
        for (int c = 0; c < 3; c++) hbf[(size_t)bn * FD + c * 256 + t] = 0;
        return;
    }
    const int b = bn / NNODE, n = bn % NNODE;
    float pl[8] = {}, pr[8] = {};
#pragma unroll
    for (int c = 0; c < 3; c++) {
        int idx = c * 256 + t;          // 0..767
        int e = idx / TTS, tt = idx % TTS;
        float x0 = x[((size_t)(b * 2 + 0) * NNODE + n) * TTS + tt];
        float x1 = x[((size_t)(b * 2 + 1) * NNODE + n) * TTS + tt];
        float s1 = Ws[e * 2] * x0 + Ws[e * 2 + 1] * x1 + bs[e];
        float s2 = Wc[e * 2] * x0 + Wc[e * 2 + 1] * x1 + bc[e];
        s2 = s2 > 0.f ? s2 : 0.01f * s2;
        float v = s1 + s2;
        h0[(size_t)bn * FD + idx] = v;
        hbf[(size_t)bn * FD + idx] = f2b(v);
#pragma unroll
        for (int hh = 0; hh < 8; hh++) {
            pl[hh] += v * wl[hh * FD + idx];
            pr[hh] += v * wr[hh * FD + idx];
        }
    }
    const int wv = t >> 6, lane = t & 63;
#pragma unroll
    for (int hh = 0; hh < 8; hh++) {
        float a = pl[hh], c2 = pr[hh];
#pragma unroll
        for (int off = 32; off > 0; off >>= 1) {
            a += __shfl_down(a, off);
            c2 += __shfl_down(c2, off);
        }
        if (lane == 0) { redl[wv][hh] = a; redr[wv][hh] = c2; }
    }
    __syncthreads();
    if (t < 8) {
        el[bn * NH + t] = redl[0][t] + redl[1][t] + redl[2][t] + redl[3][t];
        er[bn * NH + t] = redr[0][t] + redr[1][t] + redr[2][t] + redr[3][t];
    }
}

// ---------------- deterministic parallel CSR, wave-per-edge / wave-per-node ----
#define CSR_EBLK 468  // 468 blocks x 4 waves = 1872 edge-waves
__global__ __launch_bounds__(256) void build_csr3(const int* __restrict__ dst,
                                                  int* __restrict__ ptr, int* __restrict__ cidx) {
    __shared__ int dl[NEP2];
    const int t = threadIdx.x;
    const int wv = t >> 6, lane = t & 63;
    for (int i = t; i < NEP2; i += 256) dl[i] = (i < NE) ? dst[i] : 0x0FFFFFFF;
    __syncthreads();
    if (blockIdx.x < CSR_EBLK) {
        const int e = blockIdx.x * 4 + wv;
        if (e >= NE) return;
        const int d = dl[e];
        int pos = 0;
#pragma unroll
        for (int j = 0; j < 30; j++) {
            int i = lane + j * 64;
            int di = dl[i];
            pos += (int)(di < d) + (int)((i < e) & (di == d));
        }
#pragma unroll
        for (int off = 32; off > 0; off >>= 1) pos += __shfl_down(pos, off);
        if (lane == 0) cidx[pos] = e;
    } else {
        const int n = (blockIdx.x - CSR_EBLK) * 4 + wv;  // 0..207
        if (n > NNODE) return;
        int cnt = 0;
#pragma unroll
        for (int j = 0; j < 30; j++) cnt += (int)(dl[lane + j * 64] < n);
#pragma unroll
        for (int off = 32; off > 0; off >>= 1) cnt += __shfl_down(cnt, off);
        if (lane == 0) ptr[n] = cnt;  // ptr[NNODE] = NE
    }
}

// ---------------- MFMA GEMM, single-buffer + 0-conflict XOR swizzle ------------
// C = A[MP][FD] @ Bt[HFD][FD]^T. Write side = inverse-swizzled global SOURCE
// (linear LDS dest, rule #21); read side = slot ^ ((lm>>1)&3).
__global__ __launch_bounds__(256) void gemm_bf16(const unsigned short* __restrict__ A,
                                                 const unsigned short* __restrict__ Bt,
                                                 unsigned short* __restrict__ C) {
    __shared__ __align__(16) unsigned short Alds[128 * 32];
    __shared__ __align__(16) unsigned short Blds[128 * 32];
    const int t = threadIdx.x;
    const int lane = t & 63;
    const int wv = t >> 6;
    const int wr = (wv >> 1) * 64, wc = (wv & 1) * 64;
    const int mt = blockIdx.y * 128, nt = blockIdx.x * 128;
    const int lm = lane & 15;
    const int rsw = (lm >> 1) & 3;                 // read-side XOR
    const int s4 = lane >> 4;                      // k-slot 0..3
    const int rdoff = (s4 ^ rsw) * 8;

    const int r0 = (wv * 2) * 16 + (lane >> 2);
    const int r1 = (wv * 2 + 1) * 16 + (lane >> 2);
    const int cseg = (((lane & 3) ^ ((lane >> 3) & 3)) * 8);
    const size_t aoff0 = (size_t)(mt + r0) * FD + cseg;
    const size_t aoff1 = (size_t)(mt + r1) * FD + cseg;
    const size_t boff0 = (size_t)(nt + r0) * FD + cseg;
    const size_t boff1 = (size_t)(nt + r1) * FD + cseg;
    unsigned short* la0 = Alds + (size_t)(wv * 2) * 512;
    unsigned short* la1 = Alds + (size_t)(wv * 2 + 1) * 512;
    unsigned short* lb0 = Blds + (size_t)(wv * 2) * 512;
    unsigned short* lb1 = Blds + (size_t)(wv * 2 + 1) * 512;

    f32x4 acc[4][4] = {};
    for (int ks = 0; ks < FD; ks += 32) {
        __builtin_amdgcn_global_load_lds((glb_u32*)(A + aoff0 + ks), (lds_u32*)la0, 16, 0, 0);
        __builtin_amdgcn_global_load_lds((glb_u32*)(A + aoff1 + ks), (lds_u32*)la1, 16, 0, 0);
        __builtin_amdgcn_global_load_lds((glb_u32*)(Bt + boff0 + ks), (lds_u32*)lb0, 16, 0, 0);
        __builtin_amdgcn_global_load_lds((glb_u32*)(Bt + boff1 + ks), (lds_u32*)lb1, 16, 0, 0);
        __syncthreads();
        bf16x8 af[4], bfv[4];
#pragma unroll
        for (int i = 0; i < 4; i++)
            af[i] = *(const bf16x8*)(Alds + (wr + i * 16 + lm) * 32 + rdoff);
#pragma unroll
        for (int j = 0; j < 4; j++)
            bfv[j] = *(const bf16x8*)(Blds + (wc + j * 16 + lm) * 32 + rdoff);
#pragma unroll
        for (int i = 0; i < 4; i++)
#pragma unroll
            for (int j = 0; j < 4; j++)
                acc[i][j] = __builtin_amdgcn_mfma_f32_16x16x32_bf16(af[i], bfv[j], acc[i][j], 0, 0, 0);
        __syncthreads();
    }
    const int rbase = s4 * 4;
#pragma unroll
    for (int i = 0; i < 4; i++) {
#pragma unroll
        for (int r = 0; r < 4; r++) {
            int grow = mt + wr + i * 16 + rbase + r;
            if (grow < MM) {
#pragma unroll
                for (int j = 0; j < 4; j++) {
                    int gcol = nt + wc + j * 16 + lm;
                    C[(size_t)grow * HFD + gcol] = f2b(acc[i][j][r]);
                }
            }
        }
    }
}

// ---------------- edge softmax: one thread per (b,n,h) -------------------------
__global__ __launch_bounds__(256) void edge_softmax(const float* __restrict__ el, const float* __restrict__ er,
                                                    const int* __restrict__ cptr, const int* __restrict__ cidx,
                                                    const int* __restrict__ src, float* __restrict__ alp) {
    const int t = blockIdx.x * 256 + threadIdx.x;
    if (t >= BB * NNODE * NH) return;
    const int hh = t & 7;
    const int n = (t >> 3) % NNODE;
    const int b = t / (NNODE * NH);
    const float erv = er[(b * NNODE + n) * NH + hh];
    const int p0 = cptr[n], p1 = cptr[n + 1];
    float m = -1e30f;
    for (int j = p0; j < p1; j++) {
        int e = cidx[j];
        float s = el[(b * NNODE + src[e]) * NH + hh] + erv;
        s = s > 0.f ? s : 0.2f * s;
        m = fmaxf(m, s);
    }
    float den = 0.f;
    for (int j = p0; j < p1; j++) {
        int e = cidx[j];
        float s = el[(b * NNODE + src[e]) * NH + hh] + erv;
        s = s > 0.f ? s : 0.2f * s;
        float ex = expf(s - m);
        den += ex;
        alp[((size_t)b * NE + e) * NH + hh] = ex;
    }
    const float inv = 1.f / den;
    for (int j = p0; j < p1; j++) {
        int e = cidx[j];
        alp[((size_t)b * NE + e) * NH + hh] *= inv;
    }
}

// ---------------- message passing + elu + head-mean; fused layer-2 el/er -------
template <int LAST>
__global__ __launch_bounds__(256) void msg_agg(const unsigned short* __restrict__ feat,
                                               const float* __restrict__ alp,
                                               const int* __restrict__ cptr, const int* __restrict__ cidx,
                                               const int* __restrict__ src, const float* __restrict__ bias,
                                               unsigned short* __restrict__ hbf_out,
                                               const float* __restrict__ wl, const float* __restrict__ wr,
                                               float* __restrict__ el, float* __restrict__ er,
                                               const float* __restrict__ h0, float* __restrict__ out) {
    __shared__ float rstl[HFD];         // 24 KB
    __shared__ int src_l[32];
    __shared__ float alph[32][NH];
    __shared__ float redl[4][8], redr[4][8];
    // XCD-aware bijective swizzle: nwg = 3312 = 8*414, consecutive bn share batch b
    const int bn = (blockIdx.x & 7) * (MM / 8) + (blockIdx.x >> 3);
    const int b = bn / NNODE, n = bn % NNODE;
    const int t = threadIdx.x;
    const int h0i = t / 96, h1i = (256 + t) / 96, h2i = (512 + t) / 96;
    float acc[3][8] = {};
    const int p0 = cptr[n], p1 = cptr[n + 1];
    for (int base = p0; base < p1; base += 32) {
        const int cnt = min(32, p1 - base);
        if (t < cnt) src_l[t] = src[cidx[base + t]];
        {
            int j = t >> 3, hh = t & 7;
            if (j < cnt) alph[j][hh] = alp[((size_t)b * NE + cidx[base + j]) * NH + hh];
        }
        __syncthreads();
        for (int j2 = 0; j2 < cnt; j2++) {
            const size_t srow = (size_t)(b * NNODE + src_l[j2]) * HFD;
            const float a0 = alph[j2][h0i], a1 = alph[j2][h1i], a2 = alph[j2][h2i];
            uint4 pk;
            unsigned int w;
            pk = *(const uint4*)(feat + srow + (size_t)(0 * 256 + t) * 8);
            w = pk.x; acc[0][0] += a0 * b2f((unsigned short)w); acc[0][1] += a0 * b2f((unsigned short)(w >> 16));
            w = pk.y; acc[0][2] += a0 * b2f((unsigned short)w); acc[0][3] += a0 * b2f((unsigned short)(w >> 16));
            w = pk.z; acc[0][4] += a0 * b2f((unsigned short)w); acc[0][5] += a0 * b2f((unsigned short)(w >> 16));
            w = pk.w; acc[0][6] += a0 * b2f((unsigned short)w); acc[0][7] += a0 * b2f((unsigned short)(w >> 16));
            pk = *(const uint4*)(feat + srow + (size_t)(1 * 256 + t) * 8);
            w = pk.x; acc[1][0] += a1 * b2f((unsigned short)w); acc[1][1] += a1 * b2f((unsigned short)(w >> 16));
            w = pk.y; acc[1][2] += a1 * b2f((unsigned short)w); acc[1][3] += a1 * b2f((unsigned short)(w >> 16));
            w = pk.z; acc[1][4] += a1 * b2f((unsigned short)w); acc[1][5] += a1 * b2f((unsigned short)(w >> 16));
            w = pk.w; acc[1][6] += a1 * b2f((unsigned short)w); acc[1][7] += a1 * b2f((unsigned short)(w >> 16));
            pk = *(const uint4*)(feat + srow + (size_t)(2 * 256 + t) * 8);
            w = pk.x; acc[2][0] += a2 * b2f((unsigned short)w); acc[2][1] += a2 * b2f((unsigned short)(w >> 16));
            w = pk.y; acc[2][2] += a2 * b2f((unsigned short)w); acc[2][3] += a2 * b2f((unsigned short)(w >> 16));
            w = pk.z; acc[2][4] += a2 * b2f((unsigned short)w); acc[2][5] += a2 * b2f((unsigned short)(w >> 16));
            w = pk.w; acc[2][6] += a2 * b2f((unsigned short)w); acc[2][7] += a2 * b2f((unsigned short)(w >> 16));
        }
        __syncthreads();
    }
#pragma unroll
    for (int c = 0; c < 3; c++) {
        int v = c * 256 + t;
#pragma unroll
        for (int u = 0; u < 8; u++) rstl[v * 8 + u] = acc[c][u];
    }
    __syncthreads();
    float pl[8] = {}, pr[8] = {};
#pragma unroll
    for (int q = 0; q < 3; q++) {
        int f = q * 256 + t;
        float val = 0.f;
#pragma unroll
        for (int hh = 0; hh < 8; hh++) {
            float r = rstl[hh * FD + f] + bias[hh * FD + f];
            val += (r > 0.f) ? r : (expf(r) - 1.f);
        }
        val *= 0.125f;
        if (LAST) {
            int e_ = f / TTS, tt_ = f % TTS;
            out[((size_t)(b * 64 + e_) * NNODE + n) * TTS + tt_] = h0[(size_t)bn * FD + f] + val;
        } else {
            hbf_out[(size_t)bn * FD + f] = f2b(val);
#pragma unroll
            for (int hh = 0; hh < 8; hh++) {
                pl[hh] += val * wl[hh * FD + f];
                pr[hh] += val * wr[hh * FD + f];
            }
        }
    }
    if (!LAST) {
        const int wv = t >> 6, lane = t & 63;
#pragma unroll
        for (int hh = 0; hh < 8; hh++) {
            float a = pl[hh], c2 = pr[hh];
#pragma unroll
            for (int off = 32; off > 0; off >>= 1) {
                a += __shfl_down(a, off);
                c2 += __shfl_down(c2, off);
            }
            if (lane == 0) { redl[wv][hh] = a; redr[wv][hh] = c2; }
        }
        __syncthreads();
        if (t < 8) {
            el[bn * NH + t] = redl[0][t] + redl[1][t] + redl[2][t] + redl[3][t];
            er[bn * NH + t] = redr[0][t] + redr[1][t] + redr[2][t] + redr[3][t];
        }
    }
}

extern "C" void kernel_launch(void* const* d_in, const int* in_sizes, int n_in,
                              void* d_out, int out_size, void* d_ws, size_t ws_size,
                              hipStream_t stream) {
    const float* x = (const float*)d_in[0];
    const int* src = (const int*)d_in[1];
    const int* dst = (const int*)d_in[2];
    const float* Ws = (const float*)d_in[3];
    const float* bs = (const float*)d_in[4];
    const float* Wc = (const float*)d_in[5];
    const float* bc = (const float*)d_in[6];
    const float* W1 = (const float*)d_in[7];
    const float* al1 = (const float*)d_in[8];
    const float* ar1 = (const float*)d_in[9];
    const float* b1 = (const float*)d_in[10];
    const float* W2 = (const float*)d_in[11];
    const float* al2 = (const float*)d_in[12];
    const float* ar2 = (const float*)d_in[13];
    const float* b2 = (const float*)d_in[14];
    float* out = (float*)d_out;

    char* w = (char*)d_ws;
    size_t off = 0;
    auto alloc = [&](size_t bytes) -> void* {
        void* p = w + off;
        off = (off + bytes + 255) & ~(size_t)255;
        return p;
    };
    float* h0 = (float*)alloc((size_t)MM * FD * 4);
    unsigned short* hbf = (unsigned short*)alloc((size_t)MP * FD * 2);
    unsigned short* Wt1 = (unsigned short*)alloc((size_t)HFD * FD * 2);
    unsigned short* Wt2 = (unsigned short*)alloc((size_t)HFD * FD * 2);
    unsigned short* feat = (unsigned short*)alloc((size_t)MM * HFD * 2);
    float* el = (float*)alloc((size_t)MM * NH * 4);
    float* er = (float*)alloc((size_t)MM * NH * 4);
    float* alp = (float*)alloc((size_t)BB * NE * NH * 4);
    int* cptr = (int*)alloc((NNODE + 1) * 4);
    int* cidx = (int*)alloc(NE * 4);
    float* wlr = (float*)alloc((size_t)4 * 6144 * 4);  // wl1,wr1,wl2,wr2
    float* wl1 = wlr, * wr1 = wlr + 6144, * wl2 = wlr + 12288, * wr2 = wlr + 18432;

    // prep (el1/er1 fused into prep_h via wl1/wr1)
    prep_wlr<<<48, 256, 0, stream>>>(W1, al1, ar1, W2, al2, ar2, wlr);
    transpose_w2<<<dim3(12, 96, 2), 256, 0, stream>>>(W1, W2, Wt1, Wt2);
    prep_h<<<MP, 256, 0, stream>>>(x, Ws, bs, Wc, bc, wl1, wr1, h0, hbf, el, er);
    build_csr3<<<CSR_EBLK + 52, 256, 0, stream>>>(dst, cptr, cidx);

    // layer 1
    edge_softmax<<<104, 256, 0, stream>>>(el, er, cptr, cidx, src, alp);
    gemm_bf16<<<dim3(48, 26), 256, 0, stream>>>(hbf, Wt1, feat);
    msg_agg<0><<<MM, 256, 0, stream>>>(feat, alp, cptr, cidx, src, b1, hbf, wl2, wr2, el, er, nullptr, nullptr);

    // layer 2
    edge_softmax<<<104, 256, 0, stream>>>(el, er, cptr, cidx, src, alp);
    gemm_bf16<<<dim3(48, 26), 256, 0, stream>>>(hbf, Wt2, feat);
    msg_agg<1><<<MM, 256, 0, stream>>>(feat, alp, cptr, cidx, src, b2, nullptr, nullptr, nullptr, nullptr, nullptr, h0, out);
}

// Round 7
// 241.688 us; speedup vs baseline: 1.2462x; 1.2462x over previous
//
#include <hip/hip_runtime.h>

#define BB 16
#define NNODE 207
#define TTS 12
#define NE 1863
#define NEP2 1920 // NE padded to 30*64
#define NH 8
#define FD 768
#define HFD 6144
#define MM 3312   // BB*NNODE
#define MP 3328   // padded to 26*128

typedef short bf16x8 __attribute__((ext_vector_type(8)));
typedef float f32x4 __attribute__((ext_vector_type(4)));

typedef __attribute__((address_space(3))) unsigned int lds_u32;
typedef __attribute__((address_space(1))) const unsigned int glb_u32;

__device__ __forceinline__ unsigned short f2b(float f) {
    unsigned int u = __float_as_uint(f);
    u = (u + 0x7FFFu + ((u >> 16) & 1u)) >> 16;
    return (unsigned short)u;
}
__device__ __forceinline__ float b2f(unsigned short b) {
    return __uint_as_float(((unsigned int)b) << 16);
}

// ---------------- wl/wr precompute, wave-per-output ----------------------------
// wl[hh][k] = sum_f W[k][hh*768+f]*al[hh][f]; wlr layout [which][l/r][8][768].
// 12288 waves (one per which,k,hh); lane reads 3 coalesced float4s.
__global__ __launch_bounds__(256) void prep_wlr(const float* __restrict__ W1,
                                                const float* __restrict__ al1, const float* __restrict__ ar1,
                                                const float* __restrict__ W2,
                                                const float* __restrict__ al2, const float* __restrict__ ar2,
                                                float* __restrict__ wlr) {
    const int wid = blockIdx.x * 4 + (threadIdx.x >> 6);  // 0..12287
    const int lane = threadIdx.x & 63;
    const int which = wid / 6144;
    const int r = wid % 6144;
    const int k = r >> 3, hh = r & 7;
    const float* W = which ? W2 : W1;
    const float* al = which ? al2 : al1;
    const float* ar = which ? ar2 : ar1;
    const float4* wp = (const float4*)(W + (size_t)k * HFD + hh * FD);
    const float4* ap = (const float4*)(al + hh * FD);
    const float4* rp = (const float4*)(ar + hh * FD);
    float sl = 0.f, sr = 0.f;
#pragma unroll
    for (int jj = 0; jj < 3; jj++) {
        int j = lane + jj * 64;
        float4 w = wp[j], a = ap[j], b = rp[j];
        sl += w.x * a.x + w.y * a.y + w.z * a.z + w.w * a.w;
        sr += w.x * b.x + w.y * b.y + w.z * b.z + w.w * b.w;
    }
#pragma unroll
    for (int off = 32; off > 0; off >>= 1) {
        sl += __shfl_down(sl, off);
        sr += __shfl_down(sr, off);
    }
    if (lane == 0) {
        wlr[(size_t)which * 12288 + 0 + hh * FD + k] = sl;
        wlr[(size_t)which * 12288 + 6144 + hh * FD + k] = sr;
    }
}

// ---------------- W transpose (both weights): W[k][n] f32 -> Wt[n][k] bf16 -----
__global__ __launch_bounds__(256) void transpose_w2(const float* __restrict__ W1,
                                                    const float* __restrict__ W2,
                                                    unsigned short* __restrict__ Wt1,
                                                    unsigned short* __restrict__ Wt2) {
    __shared__ float tile[64][65];
    const float* W = blockIdx.z ? W2 : W1;
    unsigned short* Wt = blockIdx.z ? Wt2 : Wt1;
    const int k0 = blockIdx.x * 64;  // 768/64 = 12
    const int n0 = blockIdx.y * 64;  // 6144/64 = 96
    const int c = threadIdx.x & 63, r0 = threadIdx.x >> 6;
#pragma unroll
    for (int i = 0; i < 16; i++) {
        int r = r0 + i * 4;
        tile[r][c] = W[(size_t)(k0 + r) * HFD + n0 + c];
    }
    __syncthreads();
#pragma unroll
    for (int i = 0; i < 16; i++) {
        int r = r0 + i * 4;
        Wt[(size_t)(n0 + r) * FD + k0 + c] = f2b(tile[c][r]);
    }
}

// ---------------- 1x1 convs -> h0, hbf; fused layer-1 el/er --------------------
__global__ __launch_bounds__(256) void prep_h(const float* __restrict__ x,
                                              const float* __restrict__ Ws, const float* __restrict__ bs,
                                              const float* __restrict__ Wc, const float* __restrict__ bc,
                                              const float* __restrict__ wl, const float* __restrict__ wr,
                                              float* __restrict__ h0, unsigned short* __restrict__ hbf,
                                              float* __restrict__ el, float* __restrict__ er) {
    __shared__ float redl[4][8], redr[4][8];
    const int bn = blockIdx.x;
    const int t = threadIdx.x;
    if (bn >= MM) {
#pragma unroll
        for (int c = 0; c < 3; c++) hbf[(size_t)bn * FD + c * 256 + t] = 0;
        return;
    }
    const int b = bn / NNODE, n = bn % NNODE;
    float pl[8] = {}, pr[8] = {};
#pragma unroll
    for (int c = 0; c < 3; c++) {
        int idx = c * 256 + t;          // 0..767
        int e = idx / TTS, tt = idx % TTS;
        float x0 = x[((size_t)(b * 2 + 0) * NNODE + n) * TTS + tt];
        float x1 = x[((size_t)(b * 2 + 1) * NNODE + n) * TTS + tt];
        float s1 = Ws[e * 2] * x0 + Ws[e * 2 + 1] * x1 + bs[e];
        float s2 = Wc[e * 2] * x0 + Wc[e * 2 + 1] * x1 + bc[e];
        s2 = s2 > 0.f ? s2 : 0.01f * s2;
        float v = s1 + s2;
        h0[(size_t)bn * FD + idx] = v;
        hbf[(size_t)bn * FD + idx] = f2b(v);
#pragma unroll
        for (int hh = 0; hh < 8; hh++) {
            pl[hh] += v * wl[hh * FD + idx];
            pr[hh] += v * wr[hh * FD + idx];
        }
    }
    const int wv = t >> 6, lane = t & 63;
#pragma unroll
    for (int hh = 0; hh < 8; hh++) {
        float a = pl[hh], c2 = pr[hh];
#pragma unroll
        for (int off = 32; off > 0; off >>= 1) {
            a += __shfl_down(a, off);
            c2 += __shfl_down(c2, off);
        }
        if (lane == 0) { redl[wv][hh] = a; redr[wv][hh] = c2; }
    }
    __syncthreads();
    if (t < 8) {
        el[bn * NH + t] = redl[0][t] + redl[1][t] + redl[2][t] + redl[3][t];
        er[bn * NH + t] = redr[0][t] + redr[1][t] + redr[2][t] + redr[3][t];
    }
}

// ---------------- deterministic parallel CSR, wave-per-edge / wave-per-node ----
#define CSR_EBLK 468  // 468 blocks x 4 waves = 1872 edge-waves
__global__ __launch_bounds__(256) void build_csr3(const int* __restrict__ dst,
                                                  int* __restrict__ ptr, int* __restrict__ cidx) {
    __shared__ int dl[NEP2];
    const int t = threadIdx.x;
    const int wv = t >> 6, lane = t & 63;
    for (int i = t; i < NEP2; i += 256) dl[i] = (i < NE) ? dst[i] : 0x0FFFFFFF;
    __syncthreads();
    if (blockIdx.x < CSR_EBLK) {
        const int e = blockIdx.x * 4 + wv;
        if (e >= NE) return;
        const int d = dl[e];
        int pos = 0;
#pragma unroll
        for (int j = 0; j < 30; j++) {
            int i = lane + j * 64;
            int di = dl[i];
            pos += (int)(di < d) + (int)((i < e) & (di == d));
        }
#pragma unroll
        for (int off = 32; off > 0; off >>= 1) pos += __shfl_down(pos, off);
        if (lane == 0) cidx[pos] = e;
    } else {
        const int n = (blockIdx.x - CSR_EBLK) * 4 + wv;  // 0..207
        if (n > NNODE) return;
        int cnt = 0;
#pragma unroll
        for (int j = 0; j < 30; j++) cnt += (int)(dl[lane + j * 64] < n);
#pragma unroll
        for (int off = 32; off > 0; off >>= 1) cnt += __shfl_down(cnt, off);
        if (lane == 0) ptr[n] = cnt;  // ptr[NNODE] = NE
    }
}

// ---------------- MFMA GEMM, single-buffer + 0-conflict XOR swizzle ------------
// C = A[MP][FD] @ Bt[HFD][FD]^T. Write side = inverse-swizzled global SOURCE
// (linear LDS dest, rule #21); read side = slot ^ ((lm>>1)&3).
__global__ __launch_bounds__(256) void gemm_bf16(const unsigned short* __restrict__ A,
                                                 const unsigned short* __restrict__ Bt,
                                                 unsigned short* __restrict__ C) {
    __shared__ __align__(16) unsigned short Alds[128 * 32];
    __shared__ __align__(16) unsigned short Blds[128 * 32];
    const int t = threadIdx.x;
    const int lane = t & 63;
    const int wv = t >> 6;
    const int wr = (wv >> 1) * 64, wc = (wv & 1) * 64;
    const int mt = blockIdx.y * 128, nt = blockIdx.x * 128;
    const int lm = lane & 15;
    const int rsw = (lm >> 1) & 3;                 // read-side XOR
    const int s4 = lane >> 4;                      // k-slot 0..3
    const int rdoff = (s4 ^ rsw) * 8;

    const int r0 = (wv * 2) * 16 + (lane >> 2);
    const int r1 = (wv * 2 + 1) * 16 + (lane >> 2);
    const int cseg = (((lane & 3) ^ ((lane >> 3) & 3)) * 8);
    const size_t aoff0 = (size_t)(mt + r0) * FD + cseg;
    const size_t aoff1 = (size_t)(mt + r1) * FD + cseg;
    const size_t boff0 = (size_t)(nt + r0) * FD + cseg;
    const size_t boff1 = (size_t)(nt + r1) * FD + cseg;
    unsigned short* la0 = Alds + (size_t)(wv * 2) * 512;
    unsigned short* la1 = Alds + (size_t)(wv * 2 + 1) * 512;
    unsigned short* lb0 = Blds + (size_t)(wv * 2) * 512;
    unsigned short* lb1 = Blds + (size_t)(wv * 2 + 1) * 512;

    f32x4 acc[4][4] = {};
    for (int ks = 0; ks < FD; ks += 32) {
        __builtin_amdgcn_global_load_lds((glb_u32*)(A + aoff0 + ks), (lds_u32*)la0, 16, 0, 0);
        __builtin_amdgcn_global_load_lds((glb_u32*)(A + aoff1 + ks), (lds_u32*)la1, 16, 0, 0);
        __builtin_amdgcn_global_load_lds((glb_u32*)(Bt + boff0 + ks), (lds_u32*)lb0, 16, 0, 0);
        __builtin_amdgcn_global_load_lds((glb_u32*)(Bt + boff1 + ks), (lds_u32*)lb1, 16, 0, 0);
        __syncthreads();
        bf16x8 af[4], bfv[4];
#pragma unroll
        for (int i = 0; i < 4; i++)
            af[i] = *(const bf16x8*)(Alds + (wr + i * 16 + lm) * 32 + rdoff);
#pragma unroll
        for (int j = 0; j < 4; j++)
            bfv[j] = *(const bf16x8*)(Blds + (wc + j * 16 + lm) * 32 + rdoff);
#pragma unroll
        for (int i = 0; i < 4; i++)
#pragma unroll
            for (int j = 0; j < 4; j++)
                acc[i][j] = __builtin_amdgcn_mfma_f32_16x16x32_bf16(af[i], bfv[j], acc[i][j], 0, 0, 0);
        __syncthreads();
    }
    const int rbase = s4 * 4;
#pragma unroll
    for (int i = 0; i < 4; i++) {
#pragma unroll
        for (int r = 0; r < 4; r++) {
            int grow = mt + wr + i * 16 + rbase + r;
            if (grow < MM) {
#pragma unroll
                for (int j = 0; j < 4; j++) {
                    int gcol = nt + wc + j * 16 + lm;
                    C[(size_t)grow * HFD + gcol] = f2b(acc[i][j][r]);
                }
            }
        }
    }
}

// ---------------- edge softmax: one thread per (b,n,h) -------------------------
__global__ __launch_bounds__(256) void edge_softmax(const float* __restrict__ el, const float* __restrict__ er,
                                                    const int* __restrict__ cptr, const int* __restrict__ cidx,
                                                    const int* __restrict__ src, float* __restrict__ alp) {
    const int t = blockIdx.x * 256 + threadIdx.x;
    if (t >= BB * NNODE * NH) return;
    const int hh = t & 7;
    const int n = (t >> 3) % NNODE;
    const int b = t / (NNODE * NH);
    const float erv = er[(b * NNODE + n) * NH + hh];
    const int p0 = cptr[n], p1 = cptr[n + 1];
    float m = -1e30f;
    for (int j = p0; j < p1; j++) {
        int e = cidx[j];
        float s = el[(b * NNODE + src[e]) * NH + hh] + erv;
        s = s > 0.f ? s : 0.2f * s;
        m = fmaxf(m, s);
    }
    float den = 0.f;
    for (int j = p0; j < p1; j++) {
        int e = cidx[j];
        float s = el[(b * NNODE + src[e]) * NH + hh] + erv;
        s = s > 0.f ? s : 0.2f * s;
        float ex = expf(s - m);
        den += ex;
        alp[((size_t)b * NE + e) * NH + hh] = ex;
    }
    const float inv = 1.f / den;
    for (int j = p0; j < p1; j++) {
        int e = cidx[j];
        alp[((size_t)b * NE + e) * NH + hh] *= inv;
    }
}

// ---------------- message passing + elu + head-mean; fused layer-2 el/er -------
template <int LAST>
__global__ __launch_bounds__(256) void msg_agg(const unsigned short* __restrict__ feat,
                                               const float* __restrict__ alp,
                                               const int* __restrict__ cptr, const int* __restrict__ cidx,
                                               const int* __restrict__ src, const float* __restrict__ bias,
                                               unsigned short* __restrict__ hbf_out,
                                               const float* __restrict__ wl, const float* __restrict__ wr,
                                               float* __restrict__ el, float* __restrict__ er,
                                               const float* __restrict__ h0, float* __restrict__ out) {
    __shared__ float rstl[HFD];         // 24 KB
    __shared__ int src_l[32];
    __shared__ float alph[32][NH];
    __shared__ float redl[4][8], redr[4][8];
    // XCD-aware bijective swizzle: nwg = 3312 = 8*414, consecutive bn share batch b
    const int bn = (blockIdx.x & 7) * (MM / 8) + (blockIdx.x >> 3);
    const int b = bn / NNODE, n = bn % NNODE;
    const int t = threadIdx.x;
    const int h0i = t / 96, h1i = (256 + t) / 96, h2i = (512 + t) / 96;
    float acc[3][8] = {};
    const int p0 = cptr[n], p1 = cptr[n + 1];
    for (int base = p0; base < p1; base += 32) {
        const int cnt = min(32, p1 - base);
        if (t < cnt) src_l[t] = src[cidx[base + t]];
        {
            int j = t >> 3, hh = t & 7;
            if (j < cnt) alph[j][hh] = alp[((size_t)b * NE + cidx[base + j]) * NH + hh];
        }
        __syncthreads();
        for (int j2 = 0; j2 < cnt; j2++) {
            const size_t srow = (size_t)(b * NNODE + src_l[j2]) * HFD;
            const float a0 = alph[j2][h0i], a1 = alph[j2][h1i], a2 = alph[j2][h2i];
            uint4 pk;
            unsigned int w;
            pk = *(const uint4*)(feat + srow + (size_t)(0 * 256 + t) * 8);
            w = pk.x; acc[0][0] += a0 * b2f((unsigned short)w); acc[0][1] += a0 * b2f((unsigned short)(w >> 16));
            w = pk.y; acc[0][2] += a0 * b2f((unsigned short)w); acc[0][3] += a0 * b2f((unsigned short)(w >> 16));
            w = pk.z; acc[0][4] += a0 * b2f((unsigned short)w); acc[0][5] += a0 * b2f((unsigned short)(w >> 16));
            w = pk.w; acc[0][6] += a0 * b2f((unsigned short)w); acc[0][7] += a0 * b2f((unsigned short)(w >> 16));
            pk = *(const uint4*)(feat + srow + (size_t)(1 * 256 + t) * 8);
            w = pk.x; acc[1][0] += a1 * b2f((unsigned short)w); acc[1][1] += a1 * b2f((unsigned short)(w >> 16));
            w = pk.y; acc[1][2] += a1 * b2f((unsigned short)w); acc[1][3] += a1 * b2f((unsigned short)(w >> 16));
            w = pk.z; acc[1][4] += a1 * b2f((unsigned short)w); acc[1][5] += a1 * b2f((unsigned short)(w >> 16));
            w = pk.w; acc[1][6] += a1 * b2f((unsigned short)w); acc[1][7] += a1 * b2f((unsigned short)(w >> 16));
            pk = *(const uint4*)(feat + srow + (size_t)(2 * 256 + t) * 8);
            w = pk.x; acc[2][0] += a2 * b2f((unsigned short)w); acc[2][1] += a2 * b2f((unsigned short)(w >> 16));
            w = pk.y; acc[2][2] += a2 * b2f((unsigned short)w); acc[2][3] += a2 * b2f((unsigned short)(w >> 16));
            w = pk.z; acc[2][4] += a2 * b2f((unsigned short)w); acc[2][5] += a2 * b2f((unsigned short)(w >> 16));
            w = pk.w; acc[2][6] += a2 * b2f((unsigned short)w); acc[2][7] += a2 * b2f((unsigned short)(w >> 16));
        }
        __syncthreads();
    }
#pragma unroll
    for (int c = 0; c < 3; c++) {
        int v = c * 256 + t;
#pragma unroll
        for (int u = 0; u < 8; u++) rstl[v * 8 + u] = acc[c][u];
    }
    __syncthreads();
    float pl[8] = {}, pr[8] = {};
#pragma unroll
    for (int q = 0; q < 3; q++) {
        int f = q * 256 + t;
        float val = 0.f;
#pragma unroll
        for (int hh = 0; hh < 8; hh++) {
            float r = rstl[hh * FD + f] + bias[hh * FD + f];
            val += (r > 0.f) ? r : (expf(r) - 1.f);
        }
        val *= 0.125f;
        if (LAST) {
            int e_ = f / TTS, tt_ = f % TTS;
            out[((size_t)(b * 64 + e_) * NNODE + n) * TTS + tt_] = h0[(size_t)bn * FD + f] + val;
        } else {
            hbf_out[(size_t)bn * FD + f] = f2b(val);
#pragma unroll
            for (int hh = 0; hh < 8; hh++) {
                pl[hh] += val * wl[hh * FD + f];
                pr[hh] += val * wr[hh * FD + f];
            }
        }
    }
    if (!LAST) {
        const int wv = t >> 6, lane = t & 63;
#pragma unroll
        for (int hh = 0; hh < 8; hh++) {
            float a = pl[hh], c2 = pr[hh];
#pragma unroll
            for (int off = 32; off > 0; off >>= 1) {
                a += __shfl_down(a, off);
                c2 += __shfl_down(c2, off);
            }
            if (lane == 0) { redl[wv][hh] = a; redr[wv][hh] = c2; }
        }
        __syncthreads();
        if (t < 8) {
            el[bn * NH + t] = redl[0][t] + redl[1][t] + redl[2][t] + redl[3][t];
            er[bn * NH + t] = redr[0][t] + redr[1][t] + redr[2][t] + redr[3][t];
        }
    }
}

extern "C" void kernel_launch(void* const* d_in, const int* in_sizes, int n_in,
                              void* d_out, int out_size, void* d_ws, size_t ws_size,
                              hipStream_t stream) {
    const float* x = (const float*)d_in[0];
    const int* src = (const int*)d_in[1];
    const int* dst = (const int*)d_in[2];
    const float* Ws = (const float*)d_in[3];
    const float* bs = (const float*)d_in[4];
    const float* Wc = (const float*)d_in[5];
    const float* bc = (const float*)d_in[6];
    const float* W1 = (const float*)d_in[7];
    const float* al1 = (const float*)d_in[8];
    const float* ar1 = (const float*)d_in[9];
    const float* b1 = (const float*)d_in[10];
    const float* W2 = (const float*)d_in[11];
    const float* al2 = (const float*)d_in[12];
    const float* ar2 = (const float*)d_in[13];
    const float* b2 = (const float*)d_in[14];
    float* out = (float*)d_out;

    char* w = (char*)d_ws;
    size_t off = 0;
    auto alloc = [&](size_t bytes) -> void* {
        void* p = w + off;
        off = (off + bytes + 255) & ~(size_t)255;
        return p;
    };
    float* h0 = (float*)alloc((size_t)MM * FD * 4);
    unsigned short* hbf = (unsigned short*)alloc((size_t)MP * FD * 2);
    unsigned short* Wt1 = (unsigned short*)alloc((size_t)HFD * FD * 2);
    unsigned short* Wt2 = (unsigned short*)alloc((size_t)HFD * FD * 2);
    unsigned short* feat = (unsigned short*)alloc((size_t)MM * HFD * 2);
    float* el = (float*)alloc((size_t)MM * NH * 4);
    float* er = (float*)alloc((size_t)MM * NH * 4);
    float* alp = (float*)alloc((size_t)BB * NE * NH * 4);
    int* cptr = (int*)alloc((NNODE + 1) * 4);
    int* cidx = (int*)alloc(NE * 4);
    float* wlr = (float*)alloc((size_t)4 * 6144 * 4);  // wl1,wr1,wl2,wr2
    float* wl1 = wlr, * wr1 = wlr + 6144, * wl2 = wlr + 12288, * wr2 = wlr + 18432;

    // prep (el1/er1 fused into prep_h via wl1/wr1)
    prep_wlr<<<3072, 256, 0, stream>>>(W1, al1, ar1, W2, al2, ar2, wlr);
    transpose_w2<<<dim3(12, 96, 2), 256, 0, stream>>>(W1, W2, Wt1, Wt2);
    prep_h<<<MP, 256, 0, stream>>>(x, Ws, bs, Wc, bc, wl1, wr1, h0, hbf, el, er);
    build_csr3<<<CSR_EBLK + 52, 256, 0, stream>>>(dst, cptr, cidx);

    // layer 1
    edge_softmax<<<104, 256, 0, stream>>>(el, er, cptr, cidx, src, alp);
    gemm_bf16<<<dim3(48, 26), 256, 0, stream>>>(hbf, Wt1, feat);
    msg_agg<0><<<MM, 256, 0, stream>>>(feat, alp, cptr, cidx, src, b1, hbf, wl2, wr2, el, er, nullptr, nullptr);

    // layer 2
    edge_softmax<<<104, 256, 0, stream>>>(el, er, cptr, cidx, src, alp);
    gemm_bf16<<<dim3(48, 26), 256, 0, stream>>>(hbf, Wt2, feat);
    msg_agg<1><<<MM, 256, 0, stream>>>(feat, alp, cptr, cidx, src, b2, nullptr, nullptr, nullptr, nullptr, nullptr, h0, out);
}

// Round 8
// 200.205 us; speedup vs baseline: 1.5044x; 1.2072x over previous
//
#include <hip/hip_runtime.h>

#define BB 16
#define NNODE 207
#define TTS 12
#define NE 1863
#define NEP2 1920 // NE padded to 30*64
#define NH 8
#define FD 768
#define HFD 6144
#define MM 3312   // BB*NNODE
#define MP 3328   // padded to 26*128

typedef short bf16x8 __attribute__((ext_vector_type(8)));
typedef float f32x4 __attribute__((ext_vector_type(4)));

typedef __attribute__((address_space(3))) unsigned int lds_u32;
typedef __attribute__((address_space(1))) const unsigned int glb_u32;

__device__ __forceinline__ unsigned short f2b(float f) {
    unsigned int u = __float_as_uint(f);
    u = (u + 0x7FFFu + ((u >> 16) & 1u)) >> 16;
    return (unsigned short)u;
}
__device__ __forceinline__ float b2f(unsigned short b) {
    return __uint_as_float(((unsigned int)b) << 16);
}

// ---------------- merged prep: wlr precompute | W transpose | CSR build --------
// blocks [0,3072): prep_wlr (wave-per-output)
// blocks [3072,5376): transpose W1/W2 -> Wt1/Wt2 bf16
// blocks [5376,5896): build_csr (468 edge-blocks + 52 node-blocks)
#define CSR_EBLK 468
__global__ __launch_bounds__(256) void prep_misc(const float* __restrict__ W1,
                                                 const float* __restrict__ al1, const float* __restrict__ ar1,
                                                 const float* __restrict__ W2,
                                                 const float* __restrict__ al2, const float* __restrict__ ar2,
                                                 float* __restrict__ wlr,
                                                 unsigned short* __restrict__ Wt1,
                                                 unsigned short* __restrict__ Wt2,
                                                 const int* __restrict__ dst,
                                                 int* __restrict__ ptr, int* __restrict__ cidx) {
    __shared__ __align__(16) char smem[16640];
    const int bid = blockIdx.x;
    const int t = threadIdx.x;
    const int wv = t >> 6, lane = t & 63;
    if (bid < 3072) {
        // ---- wl/wr: wl[hh][k] = sum_f W[k][hh*768+f]*al[hh][f]; [which][l/r][8][768]
        const int wid = bid * 4 + wv;   // 0..12287
        const int which = wid / 6144;
        const int r = wid % 6144;
        const int k = r >> 3, hh = r & 7;
        const float* W = which ? W2 : W1;
        const float* al = which ? al2 : al1;
        const float* ar = which ? ar2 : ar1;
        const float4* wp = (const float4*)(W + (size_t)k * HFD + hh * FD);
        const float4* ap = (const float4*)(al + hh * FD);
        const float4* rp = (const float4*)(ar + hh * FD);
        float sl = 0.f, sr = 0.f;
#pragma unroll
        for (int jj = 0; jj < 3; jj++) {
            int j = lane + jj * 64;
            float4 w = wp[j], a = ap[j], b = rp[j];
            sl += w.x * a.x + w.y * a.y + w.z * a.z + w.w * a.w;
            sr += w.x * b.x + w.y * b.y + w.z * b.z + w.w * b.w;
        }
#pragma unroll
        for (int off = 32; off > 0; off >>= 1) {
            sl += __shfl_down(sl, off);
            sr += __shfl_down(sr, off);
        }
        if (lane == 0) {
            wlr[(size_t)which * 12288 + 0 + hh * FD + k] = sl;
            wlr[(size_t)which * 12288 + 6144 + hh * FD + k] = sr;
        }
    } else if (bid < 5376) {
        // ---- transpose: W[k][n] f32 -> Wt[n][k] bf16
        float (*tile)[65] = (float(*)[65])smem;
        const int idx = bid - 3072;             // 0..2303
        const int which = idx / 1152;
        const int r2 = idx % 1152;
        const int k0 = (r2 % 12) * 64;
        const int n0 = (r2 / 12) * 64;
        const float* W = which ? W2 : W1;
        unsigned short* Wt = which ? Wt2 : Wt1;
        const int c = t & 63, r0 = t >> 6;
#pragma unroll
        for (int i = 0; i < 16; i++) {
            int r = r0 + i * 4;
            tile[r][c] = W[(size_t)(k0 + r) * HFD + n0 + c];
        }
        __syncthreads();
#pragma unroll
        for (int i = 0; i < 16; i++) {
            int r = r0 + i * 4;
            Wt[(size_t)(n0 + r) * FD + k0 + c] = f2b(tile[c][r]);
        }
    } else {
        // ---- CSR: pos(e) = #{dst<d} + #{e'<e, dst==d}; ptr[n] = #{dst<n}
        int* dl = (int*)smem;
        const int b2 = bid - 5376;              // 0..519
        for (int i = t; i < NEP2; i += 256) dl[i] = (i < NE) ? dst[i] : 0x0FFFFFFF;
        __syncthreads();
        if (b2 < CSR_EBLK) {
            const int e = b2 * 4 + wv;
            if (e >= NE) return;
            const int d = dl[e];
            int pos = 0;
#pragma unroll
            for (int j = 0; j < 30; j++) {
                int i = lane + j * 64;
                int di = dl[i];
                pos += (int)(di < d) + (int)((i < e) & (di == d));
            }
#pragma unroll
            for (int off = 32; off > 0; off >>= 1) pos += __shfl_down(pos, off);
            if (lane == 0) cidx[pos] = e;
        } else {
            const int n = (b2 - CSR_EBLK) * 4 + wv;  // 0..207
            if (n > NNODE) return;
            int cnt = 0;
#pragma unroll
            for (int j = 0; j < 30; j++) cnt += (int)(dl[lane + j * 64] < n);
#pragma unroll
            for (int off = 32; off > 0; off >>= 1) cnt += __shfl_down(cnt, off);
            if (lane == 0) ptr[n] = cnt;  // ptr[NNODE] = NE
        }
    }
}

// ---------------- 1x1 convs -> h0, hbf; fused layer-1 el/er --------------------
__global__ __launch_bounds__(256) void prep_h(const float* __restrict__ x,
                                              const float* __restrict__ Ws, const float* __restrict__ bs,
                                              const float* __restrict__ Wc, const float* __restrict__ bc,
                                              const float* __restrict__ wl, const float* __restrict__ wr,
                                              float* __restrict__ h0, unsigned short* __restrict__ hbf,
                                              float* __restrict__ el, float* __restrict__ er) {
    __shared__ float redl[4][8], redr[4][8];
    const int bn = blockIdx.x;
    const int t = threadIdx.x;
    if (bn >= MM) {
#pragma unroll
        for (int c = 0; c < 3; c++) hbf[(size_t)bn * FD + c * 256 + t] = 0;
        return;
    }
    const int b = bn / NNODE, n = bn % NNODE;
    float pl[8] = {}, pr[8] = {};
#pragma unroll
    for (int c = 0; c < 3; c++) {
        int idx = c * 256 + t;          // 0..767
        int e = idx / TTS, tt = idx % TTS;
        float x0 = x[((size_t)(b * 2 + 0) * NNODE + n) * TTS + tt];
        float x1 = x[((size_t)(b * 2 + 1) * NNODE + n) * TTS + tt];
        float s1 = Ws[e * 2] * x0 + Ws[e * 2 + 1] * x1 + bs[e];
        float s2 = Wc[e * 2] * x0 + Wc[e * 2 + 1] * x1 + bc[e];
        s2 = s2 > 0.f ? s2 : 0.01f * s2;
        float v = s1 + s2;
        h0[(size_t)bn * FD + idx] = v;
        hbf[(size_t)bn * FD + idx] = f2b(v);
#pragma unroll
        for (int hh = 0; hh < 8; hh++) {
            pl[hh] += v * wl[hh * FD + idx];
            pr[hh] += v * wr[hh * FD + idx];
        }
    }
    const int wv = t >> 6, lane = t & 63;
#pragma unroll
    for (int hh = 0; hh < 8; hh++) {
        float a = pl[hh], c2 = pr[hh];
#pragma unroll
        for (int off = 32; off > 0; off >>= 1) {
            a += __shfl_down(a, off);
            c2 += __shfl_down(c2, off);
        }
        if (lane == 0) { redl[wv][hh] = a; redr[wv][hh] = c2; }
    }
    __syncthreads();
    if (t < 8) {
        el[bn * NH + t] = redl[0][t] + redl[1][t] + redl[2][t] + redl[3][t];
        er[bn * NH + t] = redr[0][t] + redr[1][t] + redr[2][t] + redr[3][t];
    }
}

// ---------------- MFMA GEMM, BK=64 single-buffer, 3-bit XOR swizzle ------------
// C = A[MP][FD] @ Bt[HFD][FD]^T. LDS[r][slot s] holds global slot s^(r&7)
// (128B rows, 8 x 16B slots). Write: linear LDS dest + inverse-swizzled global
// source (rule #21). Read: slot = (half*4+s4) ^ (row&7) -> 2 lanes/slot per
// 16-lane quarter = 2-way = free.
__global__ __launch_bounds__(256) void gemm_bf16(const unsigned short* __restrict__ A,
                                                 const unsigned short* __restrict__ Bt,
                                                 unsigned short* __restrict__ C) {
    __shared__ __align__(16) unsigned short Alds[128 * 64];  // 16 KB
    __shared__ __align__(16) unsigned short Blds[128 * 64];  // 16 KB
    const int t = threadIdx.x;
    const int lane = t & 63;
    const int wv = t >> 6;
    const int wr = (wv >> 1) * 64, wc = (wv & 1) * 64;
    const int mt = blockIdx.y * 128, nt = blockIdx.x * 128;
    const int lm = lane & 15;
    const int s4 = lane >> 4;                       // 0..3
    const int sl0 = ((0 + s4) ^ (lm & 7)) * 8;      // k-half 0 read slot (elems)
    const int sl1 = ((4 + s4) ^ (lm & 7)) * 8;      // k-half 1

    // staging: wave wv stages chunks 4wv..4wv+3 per matrix; chunk = 8 rows x 8
    // slots (1 KB). lane i: row_in_chunk = i>>3, lds slot = i&7, global slot =
    // (i&7)^(i>>3).
    const int rr = lane >> 3;                       // 0..7
    const int ssl = ((lane & 7) ^ rr) * 8;          // global src slot offset (elems)
    const unsigned short* ap[4];
    const unsigned short* bp[4];
#pragma unroll
    for (int q = 0; q < 4; q++) {
        int row = wv * 32 + q * 8 + rr;
        ap[q] = A + (size_t)(mt + row) * FD + ssl;
        bp[q] = Bt + (size_t)(nt + row) * FD + ssl;
    }

    f32x4 acc[4][4] = {};
    for (int ks = 0; ks < FD; ks += 64) {
#pragma unroll
        for (int q = 0; q < 4; q++) {
            __builtin_amdgcn_global_load_lds((glb_u32*)(ap[q] + ks),
                (lds_u32*)(Alds + (wv * 4 + q) * 512), 16, 0, 0);
            __builtin_amdgcn_global_load_lds((glb_u32*)(bp[q] + ks),
                (lds_u32*)(Blds + (wv * 4 + q) * 512), 16, 0, 0);
        }
        __syncthreads();
        {
            bf16x8 af[4], bfv[4];
#pragma unroll
            for (int i = 0; i < 4; i++)
                af[i] = *(const bf16x8*)(Alds + (wr + i * 16 + lm) * 64 + sl0);
#pragma unroll
            for (int j = 0; j < 4; j++)
                bfv[j] = *(const bf16x8*)(Blds + (wc + j * 16 + lm) * 64 + sl0);
#pragma unroll
            for (int i = 0; i < 4; i++)
#pragma unroll
                for (int j = 0; j < 4; j++)
                    acc[i][j] = __builtin_amdgcn_mfma_f32_16x16x32_bf16(af[i], bfv[j], acc[i][j], 0, 0, 0);
        }
        {
            bf16x8 af[4], bfv[4];
#pragma unroll
            for (int i = 0; i < 4; i++)
                af[i] = *(const bf16x8*)(Alds + (wr + i * 16 + lm) * 64 + sl1);
#pragma unroll
            for (int j = 0; j < 4; j++)
                bfv[j] = *(const bf16x8*)(Blds + (wc + j * 16 + lm) * 64 + sl1);
#pragma unroll
            for (int i = 0; i < 4; i++)
#pragma unroll
                for (int j = 0; j < 4; j++)
                    acc[i][j] = __builtin_amdgcn_mfma_f32_16x16x32_bf16(af[i], bfv[j], acc[i][j], 0, 0, 0);
        }
        __syncthreads();
    }
    const int rbase = s4 * 4;
#pragma unroll
    for (int i = 0; i < 4; i++) {
#pragma unroll
        for (int r = 0; r < 4; r++) {
            int grow = mt + wr + i * 16 + rbase + r;
            if (grow < MM) {
#pragma unroll
                for (int j = 0; j < 4; j++) {
                    int gcol = nt + wc + j * 16 + lm;
                    C[(size_t)grow * HFD + gcol] = f2b(acc[i][j][r]);
                }
            }
        }
    }
}

// ---------------- message passing + fused edge softmax + elu + head-mean -------
// Wave 0 pre-phase: online softmax stats (m, den) per head over in-edges,
// 8 edges x 8 heads per pass, shfl_xor merge (strides 8/16/32 preserve lane&7).
template <int LAST>
__global__ __launch_bounds__(256) void msg_agg(const unsigned short* __restrict__ feat,
                                               const int* __restrict__ cptr, const int* __restrict__ cidx,
                                               const int* __restrict__ src, const float* __restrict__ bias,
                                               const float* __restrict__ el_in, const float* __restrict__ er_in,
                                               unsigned short* __restrict__ hbf_out,
                                               const float* __restrict__ wl, const float* __restrict__ wr,
                                               float* __restrict__ el_out, float* __restrict__ er_out,
                                               const float* __restrict__ h0, float* __restrict__ out) {
    __shared__ float rstl[HFD];         // 24 KB
    __shared__ int src_l[32];
    __shared__ float alph[32][NH];
    __shared__ float redl[4][8], redr[4][8];
    __shared__ float sm_m[8], sm_i[8], sm_er[8];
    // XCD-aware bijective swizzle: nwg = 3312 = 8*414
    const int bn = (blockIdx.x & 7) * (MM / 8) + (blockIdx.x >> 3);
    const int b = bn / NNODE, n = bn % NNODE;
    const int t = threadIdx.x;
    const int p0 = cptr[n], p1 = cptr[n + 1];
    const int deg = p1 - p0;
    if (t < 64) {
        const int h = t & 7, js = t >> 3;
        const float erv = er_in[(b * NNODE + n) * NH + h];
        float m = -1e30f, d = 0.f;
        for (int jb = 0; jb < deg; jb += 8) {
            int j = jb + js;
            float s = -1e30f;
            float add = 0.f;
            if (j < deg) {
                int e = cidx[p0 + j];
                s = el_in[(b * NNODE + src[e]) * NH + h] + erv;
                s = s > 0.f ? s : 0.2f * s;
                add = 1.f;
            }
            float mn = fmaxf(m, s);
            d = d * __expf(m - mn) + add * __expf(s - mn);
            m = mn;
        }
#pragma unroll
        for (int o = 8; o < 64; o <<= 1) {
            float mo = __shfl_xor(m, o), dd = __shfl_xor(d, o);
            float mn = fmaxf(m, mo);
            d = d * __expf(m - mn) + dd * __expf(mo - mn);
            m = mn;
        }
        if (js == 0) { sm_m[h] = m; sm_i[h] = 1.f / d; sm_er[h] = erv; }
    }
    __syncthreads();

    const int h0i = t / 96, h1i = (256 + t) / 96, h2i = (512 + t) / 96;
    float acc[3][8] = {};
    for (int base = p0; base < p1; base += 32) {
        const int cnt = min(32, p1 - base);
        if (t < cnt) src_l[t] = src[cidx[base + t]];
        {
            int j = t >> 3, hh = t & 7;
            if (j < cnt) {
                int e = cidx[base + j];
                float s = el_in[(b * NNODE + src[e]) * NH + hh] + sm_er[hh];
                s = s > 0.f ? s : 0.2f * s;
                alph[j][hh] = __expf(s - sm_m[hh]) * sm_i[hh];
            }
        }
        __syncthreads();
        for (int j2 = 0; j2 < cnt; j2++) {
            const size_t srow = (size_t)(b * NNODE + src_l[j2]) * HFD;
            const float a0 = alph[j2][h0i], a1 = alph[j2][h1i], a2 = alph[j2][h2i];
            uint4 pk;
            unsigned int w;
            pk = *(const uint4*)(feat + srow + (size_t)(0 * 256 + t) * 8);
            w = pk.x; acc[0][0] += a0 * b2f((unsigned short)w); acc[0][1] += a0 * b2f((unsigned short)(w >> 16));
            w = pk.y; acc[0][2] += a0 * b2f((unsigned short)w); acc[0][3] += a0 * b2f((unsigned short)(w >> 16));
            w = pk.z; acc[0][4] += a0 * b2f((unsigned short)w); acc[0][5] += a0 * b2f((unsigned short)(w >> 16));
            w = pk.w; acc[0][6] += a0 * b2f((unsigned short)w); acc[0][7] += a0 * b2f((unsigned short)(w >> 16));
            pk = *(const uint4*)(feat + srow + (size_t)(1 * 256 + t) * 8);
            w = pk.x; acc[1][0] += a1 * b2f((unsigned short)w); acc[1][1] += a1 * b2f((unsigned short)(w >> 16));
            w = pk.y; acc[1][2] += a1 * b2f((unsigned short)w); acc[1][3] += a1 * b2f((unsigned short)(w >> 16));
            w = pk.z; acc[1][4] += a1 * b2f((unsigned short)w); acc[1][5] += a1 * b2f((unsigned short)(w >> 16));
            w = pk.w; acc[1][6] += a1 * b2f((unsigned short)w); acc[1][7] += a1 * b2f((unsigned short)(w >> 16));
            pk = *(const uint4*)(feat + srow + (size_t)(2 * 256 + t) * 8);
            w = pk.x; acc[2][0] += a2 * b2f((unsigned short)w); acc[2][1] += a2 * b2f((unsigned short)(w >> 16));
            w = pk.y; acc[2][2] += a2 * b2f((unsigned short)w); acc[2][3] += a2 * b2f((unsigned short)(w >> 16));
            w = pk.z; acc[2][4] += a2 * b2f((unsigned short)w); acc[2][5] += a2 * b2f((unsigned short)(w >> 16));
            w = pk.w; acc[2][6] += a2 * b2f((unsigned short)w); acc[2][7] += a2 * b2f((unsigned short)(w >> 16));
        }
        __syncthreads();
    }
#pragma unroll
    for (int c = 0; c < 3; c++) {
        int v = c * 256 + t;
#pragma unroll
        for (int u = 0; u < 8; u++) rstl[v * 8 + u] = acc[c][u];
    }
    __syncthreads();
    float pl[8] = {}, pr[8] = {};
#pragma unroll
    for (int q = 0; q < 3; q++) {
        int f = q * 256 + t;
        float val = 0.f;
#pragma unroll
        for (int hh = 0; hh < 8; hh++) {
            float r = rstl[hh * FD + f] + bias[hh * FD + f];
            val += (r > 0.f) ? r : (expf(r) - 1.f);
        }
        val *= 0.125f;
        if (LAST) {
            int e_ = f / TTS, tt_ = f % TTS;
            out[((size_t)(b * 64 + e_) * NNODE + n) * TTS + tt_] = h0[(size_t)bn * FD + f] + val;
        } else {
            hbf_out[(size_t)bn * FD + f] = f2b(val);
#pragma unroll
            for (int hh = 0; hh < 8; hh++) {
                pl[hh] += val * wl[hh * FD + f];
                pr[hh] += val * wr[hh * FD + f];
            }
        }
    }
    if (!LAST) {
        const int wv = t >> 6, lane = t & 63;
#pragma unroll
        for (int hh = 0; hh < 8; hh++) {
            float a = pl[hh], c2 = pr[hh];
#pragma unroll
            for (int off = 32; off > 0; off >>= 1) {
                a += __shfl_down(a, off);
                c2 += __shfl_down(c2, off);
            }
            if (lane == 0) { redl[wv][hh] = a; redr[wv][hh] = c2; }
        }
        __syncthreads();
        if (t < 8) {
            el_out[bn * NH + t] = redl[0][t] + redl[1][t] + redl[2][t] + redl[3][t];
            er_out[bn * NH + t] = redr[0][t] + redr[1][t] + redr[2][t] + redr[3][t];
        }
    }
}

extern "C" void kernel_launch(void* const* d_in, const int* in_sizes, int n_in,
                              void* d_out, int out_size, void* d_ws, size_t ws_size,
                              hipStream_t stream) {
    const float* x = (const float*)d_in[0];
    const int* src = (const int*)d_in[1];
    const int* dst = (const int*)d_in[2];
    const float* Ws = (const float*)d_in[3];
    const float* bs = (const float*)d_in[4];
    const float* Wc = (const float*)d_in[5];
    const float* bc = (const float*)d_in[6];
    const float* W1 = (const float*)d_in[7];
    const float* al1 = (const float*)d_in[8];
    const float* ar1 = (const float*)d_in[9];
    const float* b1 = (const float*)d_in[10];
    const float* W2 = (const float*)d_in[11];
    const float* al2 = (const float*)d_in[12];
    const float* ar2 = (const float*)d_in[13];
    const float* b2 = (const float*)d_in[14];
    float* out = (float*)d_out;

    char* w = (char*)d_ws;
    size_t off = 0;
    auto alloc = [&](size_t bytes) -> void* {
        void* p = w + off;
        off = (off + bytes + 255) & ~(size_t)255;
        return p;
    };
    float* h0 = (float*)alloc((size_t)MM * FD * 4);
    unsigned short* hbf = (unsigned short*)alloc((size_t)MP * FD * 2);
    unsigned short* Wt1 = (unsigned short*)alloc((size_t)HFD * FD * 2);
    unsigned short* Wt2 = (unsigned short*)alloc((size_t)HFD * FD * 2);
    unsigned short* feat = (unsigned short*)alloc((size_t)MM * HFD * 2);
    float* el = (float*)alloc((size_t)MM * NH * 4);
    float* er = (float*)alloc((size_t)MM * NH * 4);
    float* el2 = (float*)alloc((size_t)MM * NH * 4);
    float* er2 = (float*)alloc((size_t)MM * NH * 4);
    int* cptr = (int*)alloc((NNODE + 1) * 4);
    int* cidx = (int*)alloc(NE * 4);
    float* wlr = (float*)alloc((size_t)4 * 6144 * 4);  // wl1,wr1,wl2,wr2
    float* wl1 = wlr, * wr1 = wlr + 6144, * wl2 = wlr + 12288, * wr2 = wlr + 18432;

    // prep: wlr | transpose | csr in one launch, then prep_h (needs wl1/wr1)
    prep_misc<<<5896, 256, 0, stream>>>(W1, al1, ar1, W2, al2, ar2, wlr, Wt1, Wt2, dst, cptr, cidx);
    prep_h<<<MP, 256, 0, stream>>>(x, Ws, bs, Wc, bc, wl1, wr1, h0, hbf, el, er);

    // layer 1 (softmax fused into msg_agg; el2/er2 produced for layer 2)
    gemm_bf16<<<dim3(48, 26), 256, 0, stream>>>(hbf, Wt1, feat);
    msg_agg<0><<<MM, 256, 0, stream>>>(feat, cptr, cidx, src, b1, el, er, hbf, wl2, wr2, el2, er2, nullptr, nullptr);

    // layer 2
    gemm_bf16<<<dim3(48, 26), 256, 0, stream>>>(hbf, Wt2, feat);
    msg_agg<1><<<MM, 256, 0, stream>>>(feat, cptr, cidx, src, b2, el2, er2, nullptr, nullptr, nullptr, nullptr, nullptr, h0, out);
}